// Round 7
// baseline (2315.250 us; speedup 1.0000x reference)
//
#include <hip/hip_runtime.h>
#include <stdint.h>

#define NUM_CODES 8192
#define CODE_DIM  64
#define BATCH     65536

typedef float    f32x4 __attribute__((ext_vector_type(4)));
typedef _Float16 half8 __attribute__((ext_vector_type(8)));
typedef uint32_t u32;

#define MFMA(a, b, c) __builtin_amdgcn_mfma_f32_16x16x32_f16(a, b, c, 0, 0, 0)

// ---- workspace layout (byte offsets); total = 2,162,692 B (== proven bound)
#define WS_CSQ_OFF   0u           // 8192 f32
#define WS_CNT_OFF   32768u       // 8192 f32 (histogram, zeroed)
#define WS_CBH_OFF   65536u       // 8192*64 f16 hi, chunk-swizzled
#define WS_CBL_OFF   1114112u     // 8192*64 f16 lo*2048
#define WS_LOSS_OFF  2162688u     // 1 f32

#define BUFB 33280               // 32 KB cb tile + 512 B csq tile

__device__ __forceinline__ void gload16(const void* g, void* l) {
    __builtin_amdgcn_global_load_lds(
        (const __attribute__((address_space(1))) void*)g,
        (__attribute__((address_space(3))) void*)l,
        16, 0, 0);
}

// ---------------------------------------------------------------------------
// Prep: split codebook into f16 hi + 2048*lo with chunk-XOR swizzle, + csq.
// ---------------------------------------------------------------------------
__global__ void split_cb_kernel(const float* __restrict__ cb,
                                char* __restrict__ cbh, char* __restrict__ cbl,
                                float* __restrict__ csq) {
    int gid  = blockIdx.x * 256 + threadIdx.x;   // 65536 total
    int code = gid >> 3;
    int c    = gid & 7;
    const float* p = cb + (size_t)code * CODE_DIM + c * 8;
    f32x4 u0 = *(const f32x4*)p;
    f32x4 u1 = *(const f32x4*)(p + 4);
    half8 h, lo;
    float ssq = 0.f;
#pragma unroll
    for (int i = 0; i < 4; ++i) {
        float v0 = u0[i], v1 = u1[i];
        ssq = fmaf(v0, v0, ssq); ssq = fmaf(v1, v1, ssq);
        _Float16 h0 = (_Float16)v0, h1 = (_Float16)v1;
        h[i] = h0;     h[i + 4] = h1;
        lo[i]     = (_Float16)((v0 - (float)h0) * 2048.f);
        lo[i + 4] = (_Float16)((v1 - (float)h1) * 2048.f);
    }
    int slot = code * 8 + (c ^ (code & 7));
    ((half8*)cbh)[slot] = h;
    ((half8*)cbl)[slot] = lo;
    ssq += __shfl_xor(ssq, 1, 64);
    ssq += __shfl_xor(ssq, 2, 64);
    ssq += __shfl_xor(ssq, 4, 64);
    if (c == 0) csq[code] = ssq;
}

// ---------------------------------------------------------------------------
// Fused distance + argmin via split-f16 MFMA.
// 512 thr = 8 waves (4 row-quarters x 2 code-halves); block = 256 rows.
// Per tile: 128 codes; csq tile staged through LDS (no VMEM in main loop
// besides global_load_lds). Fused: counts histogram + commitment-loss
// partial  sum(zsq + minv)  (since ||z-c||^2 = zsq + (csq - 2 z.c)).
// ---------------------------------------------------------------------------
__global__ __launch_bounds__(512, 4)
void argmin_mfma_kernel(const float* __restrict__ z, const char* __restrict__ cbh,
                        const char* __restrict__ cbl, const char* __restrict__ csq_b,
                        float* __restrict__ codes_out, float* __restrict__ ws_counts,
                        float* __restrict__ ws_loss) {
    __shared__ __align__(16) char lds[2 * BUFB];   // 66560 B
    const int tid    = threadIdx.x;
    const int lane   = tid & 63;
    const int w      = tid >> 6;          // 0..7
    const int wr     = w >> 1, wc = w & 1;
    const int lane_r = lane & 15, lg = lane >> 4;
    const int brow   = blockIdx.x * 256 + wr * 64;

    // ---- A fragments (-2z split) + per-row zsq ----
    half8 ah[4][2], al[4][2];
    float zsq[4];
#pragma unroll
    for (int m = 0; m < 4; ++m) {
        const float* zp = z + (size_t)(brow + m * 16 + lane_r) * CODE_DIM;
        float ssq = 0.f;
#pragma unroll
        for (int ks = 0; ks < 2; ++ks) {
            f32x4 u0 = *(const f32x4*)(zp + ks * 32 + lg * 8);
            f32x4 u1 = *(const f32x4*)(zp + ks * 32 + lg * 8 + 4);
            half8 h, lo;
#pragma unroll
            for (int i = 0; i < 4; ++i) {
                ssq = fmaf(u0[i], u0[i], ssq); ssq = fmaf(u1[i], u1[i], ssq);
                float a0 = -2.f * u0[i];
                _Float16 h0 = (_Float16)a0;
                h[i] = h0; lo[i] = (_Float16)((a0 - (float)h0) * 2048.f);
                float a1 = -2.f * u1[i];
                _Float16 h1 = (_Float16)a1;
                h[i + 4] = h1; lo[i + 4] = (_Float16)((a1 - (float)h1) * 2048.f);
            }
            ah[m][ks] = h; al[m][ks] = lo;
        }
        ssq += __shfl_xor(ssq, 16, 64);    // reduce across lg (k-chunks)
        ssq += __shfl_xor(ssq, 32, 64);
        zsq[m] = ssq;
    }

    float minv[16]; int mini[16];
#pragma unroll
    for (int i = 0; i < 16; ++i) { minv[i] = 3.4e38f; mini[i] = 0; }

    // ---- staging: 4 (+1) gload16 per thread per tile ----
    // prologue: tile 0 into buffer 0
    {
        char* dst = lds;
        const char* srch = cbh;
        const char* srcl = cbl;
        gload16(srch + tid * 16,         dst + tid * 16);
        gload16(srch + 8192 + tid * 16,  dst + 8192 + tid * 16);
        gload16(srcl + tid * 16,         dst + 16384 + tid * 16);
        gload16(srcl + 8192 + tid * 16,  dst + 24576 + tid * 16);
        if (tid < 32) gload16(csq_b + tid * 16, dst + 32768 + tid * 16);
    }
    __syncthreads();

    int buf = 0;
#pragma unroll 1
    for (int t = 0; t < NUM_CODES / 128; ++t) {
        if (t < NUM_CODES / 128 - 1) {
            char* dst = lds + (buf ^ 1) * BUFB;
            const char* srch = cbh + (size_t)(t + 1) * 16384;
            const char* srcl = cbl + (size_t)(t + 1) * 16384;
            gload16(srch + tid * 16,         dst + tid * 16);
            gload16(srch + 8192 + tid * 16,  dst + 8192 + tid * 16);
            gload16(srcl + tid * 16,         dst + 16384 + tid * 16);
            gload16(srcl + 8192 + tid * 16,  dst + 24576 + tid * 16);
            if (tid < 32)
                gload16(csq_b + (size_t)(t + 1) * 512 + tid * 16,
                        dst + 32768 + tid * 16);
        }

        const char*  bh_p = lds + buf * BUFB;
        const char*  bl_p = bh_p + 16384;
        const float* cs_p = (const float*)(bh_p + 32768);
        const int cbase = t * 128 + wc * 64;
#pragma unroll
        for (int n = 0; n < 4; ++n) {
            const int rt  = wc * 64 + n * 16 + lane_r;   // code within tile
            const int sw  = rt & 7;
            const int rb  = rt * 128;
            half8 bh0 = *(const half8*)(bh_p + rb + (((0 + lg) ^ sw) << 4));
            half8 bh1 = *(const half8*)(bh_p + rb + (((4 + lg) ^ sw) << 4));
            half8 bl0 = *(const half8*)(bl_p + rb + (((0 + lg) ^ sw) << 4));
            half8 bl1 = *(const half8*)(bl_p + rb + (((4 + lg) ^ sw) << 4));
            float cs  = cs_p[rt];                        // LDS, no vmcnt
            f32x4 cini = {cs, cs, cs, cs};
            f32x4 zero = {0.f, 0.f, 0.f, 0.f};
            int idxv = cbase + n * 16 + lane_r;
#pragma unroll
            for (int m = 0; m < 4; ++m) {
                f32x4 hi = MFMA(ah[m][0], bh0, cini);
                hi = MFMA(ah[m][1], bh1, hi);
                f32x4 mid = MFMA(ah[m][0], bl0, zero);
                mid = MFMA(al[m][0], bh0, mid);
                mid = MFMA(ah[m][1], bl1, mid);
                mid = MFMA(al[m][1], bh1, mid);
                f32x4 lolo = MFMA(al[m][0], bl0, zero);
                lolo = MFMA(al[m][1], bl1, lolo);
#pragma unroll
                for (int j = 0; j < 4; ++j) {
                    float s = fmaf(fmaf(lolo[j], 4.8828125e-4f, mid[j]),
                                   4.8828125e-4f, hi[j]);
                    bool lt = s < minv[m * 4 + j];
                    minv[m * 4 + j] = lt ? s : minv[m * 4 + j];
                    mini[m * 4 + j] = lt ? idxv : mini[m * 4 + j];
                }
            }
        }
        __syncthreads();
        buf ^= 1;
    }

    // ---- reduce across the 16 code-lanes ----
#pragma unroll
    for (int s = 1; s < 16; s <<= 1) {
#pragma unroll
        for (int i = 0; i < 16; ++i) {
            float ov = __shfl_xor(minv[i], s, 64);
            int   oi = __shfl_xor(mini[i], s, 64);
            if (ov < minv[i] || (ov == minv[i] && oi < mini[i])) {
                minv[i] = ov; mini[i] = oi;
            }
        }
    }

    // ---- merge wc pair via LDS; write codes/counts; loss partial ----
    float* smv = (float*)lds;              // 256 rows
    int*   smi = (int*)(lds + 1024);
    if (wc == 1 && lane_r == 0) {
#pragma unroll
        for (int m = 0; m < 4; ++m)
#pragma unroll
            for (int j = 0; j < 4; ++j) {
                int rl = wr * 64 + m * 16 + lg * 4 + j;
                smv[rl] = minv[m * 4 + j]; smi[rl] = mini[m * 4 + j];
            }
    }
    __syncthreads();
    float lsum = 0.f;
    if (wc == 0) {
        lsum = 0.25f * (zsq[0] + zsq[1] + zsq[2] + zsq[3]);  // lg-replicated x4
        if (lane_r == 0) {
#pragma unroll
            for (int m = 0; m < 4; ++m)
#pragma unroll
                for (int j = 0; j < 4; ++j) {
                    int rl = wr * 64 + m * 16 + lg * 4 + j;
                    float mv = minv[m * 4 + j]; int mi = mini[m * 4 + j];
                    float ov = smv[rl]; int oi = smi[rl];
                    if (ov < mv || (ov == mv && oi < mi)) { mv = ov; mi = oi; }
                    codes_out[blockIdx.x * 256 + rl] = (float)mi;
                    atomicAdd(&ws_counts[mi], 1.0f);
                    lsum += mv;            // ||z-c||^2 = zsq + minv
                }
        }
    }
#pragma unroll
    for (int s = 1; s < 64; s <<= 1) lsum += __shfl_xor(lsum, s, 64);
    if (lane == 0 && wc == 0) atomicAdd(ws_loss, lsum);
}

// ---------------------------------------------------------------------------
// Exclusive scan of counts -> offsets[8193] + cursor. 1 block, 256 thr,
// shfl-based (2 barriers total).
// ---------------------------------------------------------------------------
__global__ void scan_kernel(const float* __restrict__ cnt,
                            u32* __restrict__ offsets, u32* __restrict__ cursor) {
    __shared__ u32 wsum[4];
    int t = threadIdx.x, lane = t & 63, w = t >> 6;
    u32 v[32], s = 0;
#pragma unroll
    for (int i = 0; i < 32; ++i) { v[i] = (u32)cnt[t * 32 + i]; s += v[i]; }
    u32 inc = s;
#pragma unroll
    for (int d = 1; d < 64; d <<= 1) {
        u32 x = __shfl_up(inc, d, 64);
        if (lane >= d) inc += x;
    }
    if (lane == 63) wsum[w] = inc;
    __syncthreads();
    u32 base = 0;
    for (int i = 0; i < w; ++i) base += wsum[i];
    u32 excl = base + inc - s;
#pragma unroll
    for (int i = 0; i < 32; ++i) {
        offsets[t * 32 + i] = excl;
        cursor [t * 32 + i] = excl;
        excl += v[i];
    }
    if (t == 255) offsets[8192] = excl;
}

// ---------------------------------------------------------------------------
// Place rows into code-sorted order: one atomic per row.
// ---------------------------------------------------------------------------
__global__ void place_kernel(const float* __restrict__ codes_f,
                             u32* __restrict__ cursor, u32* __restrict__ rowidx) {
    int row = blockIdx.x * 256 + threadIdx.x;
    int c = (int)codes_f[row];
    u32 pos = atomicAdd(&cursor[c], 1u);
    rowidx[pos] = (u32)row;
}

// ---------------------------------------------------------------------------
// Segmented sum + z_q write: one wave per code, lane = dim. Zero atomics.
// asum fully written (empty segments -> 0), so no memset needed.
// ---------------------------------------------------------------------------
__global__ void segsum_zq_kernel(const float* __restrict__ z,
                                 const float* __restrict__ cb,
                                 const u32* __restrict__ rowidx,
                                 const u32* __restrict__ offsets,
                                 float* __restrict__ zq_out,
                                 float* __restrict__ asum) {
    int gw   = (blockIdx.x * 256 + threadIdx.x) >> 6;   // code id
    int lane = threadIdx.x & 63;
    float cbv = cb[(size_t)gw * CODE_DIM + lane];
    u32 beg = offsets[gw], end = offsets[gw + 1];
    float acc = 0.f;
    for (u32 i = beg; i < end; ++i) {
        u32 r = rowidx[i];
        acc += z[(size_t)r * CODE_DIM + lane];
        zq_out[(size_t)r * CODE_DIM + lane] = cbv;
    }
    asum[(size_t)gw * CODE_DIM + lane] = acc;
}

// ---------------------------------------------------------------------------
// EMA finalize + losses. asum aliases out_weight (read-then-overwrite).
// ---------------------------------------------------------------------------
__global__ void finalize_kernel(const float* __restrict__ ema_count,
                                const float* __restrict__ ema_weight,
                                const float* __restrict__ usage,
                                const float* __restrict__ ws_counts,
                                const float* __restrict__ ws_loss,
                                float* __restrict__ out_codebook, float* __restrict__ out_count,
                                float* __restrict__ out_weight,   float* __restrict__ out_usage,
                                float* __restrict__ out_losses) {
    int gid = blockIdx.x * 256 + threadIdx.x;
    if (gid >= NUM_CODES * CODE_DIM) return;
    int c = gid >> 6;
    float cnt  = ws_counts[c];
    float ncnt = 0.99f * ema_count[c] + 0.01f * cnt;
    float nw   = 0.99f * ema_weight[gid] + 0.01f * out_weight[gid];  // asum alias
    out_weight[gid]   = nw;
    out_codebook[gid] = nw / (ncnt + 1e-5f);
    if ((gid & 63) == 0) {
        out_count[c] = ncnt;
        out_usage[c] = usage[c] + cnt;
    }
    if (gid == 0) {
        float s = ws_loss[0] * (1.0f / ((float)BATCH * (float)CODE_DIM));
        out_losses[0] = s;
        out_losses[1] = s;
        out_losses[2] = fmaf(0.25f, s, s);
    }
}

// ---------------------------------------------------------------------------
extern "C" void kernel_launch(void* const* d_in, const int* in_sizes, int n_in,
                              void* d_out, int out_size, void* d_ws, size_t ws_size,
                              hipStream_t stream) {
    const float* z     = (const float*)d_in[0];
    const float* cb    = (const float*)d_in[1];
    const float* emac  = (const float*)d_in[2];
    const float* emaw  = (const float*)d_in[3];
    const float* usage = (const float*)d_in[4];

    float* out = (float*)d_out;
    float* o_zq    = out;                    // 4194304
    float* o_codes = out + 4194304;          // 65536
    float* o_loss  = out + 4194304 + 65536;  // 3
    float* o_cb    = o_loss + 3;             // 524288 (scratch until finalize)
    float* o_cnt   = o_cb + 524288;          // 8192
    float* o_w     = o_cnt + 8192;           // 524288 (asum, then weight)
    float* o_use   = o_w + 524288;           // 8192

    // sort scratch inside o_cb region (finalize overwrites it last)
    u32* rowidx  = (u32*)o_cb;               // [0, 65536)
    u32* offsets = rowidx + 65536;           // [65536, 73729)
    u32* cursor  = rowidx + 81920;           // [81920, 90112)

    char*  wsb     = (char*)d_ws;
    float* ws_csq  = (float*)(wsb + WS_CSQ_OFF);
    float* ws_cnt  = (float*)(wsb + WS_CNT_OFF);
    char*  ws_cbh  = wsb + WS_CBH_OFF;
    char*  ws_cbl  = wsb + WS_CBL_OFF;
    float* ws_loss = (float*)(wsb + WS_LOSS_OFF);

    hipMemsetAsync(wsb + WS_CNT_OFF, 0, 32768, stream);   // counts histogram
    hipMemsetAsync(wsb + WS_LOSS_OFF, 0, 4, stream);      // loss accumulator

    split_cb_kernel<<<256, 256, 0, stream>>>(cb, ws_cbh, ws_cbl, ws_csq);
    argmin_mfma_kernel<<<BATCH / 256, 512, 0, stream>>>(
        z, ws_cbh, ws_cbl, (const char*)ws_csq, o_codes, ws_cnt, ws_loss);
    scan_kernel<<<1, 256, 0, stream>>>(ws_cnt, offsets, cursor);
    place_kernel<<<BATCH / 256, 256, 0, stream>>>(o_codes, cursor, rowidx);
    segsum_zq_kernel<<<NUM_CODES * 64 / 256, 256, 0, stream>>>(
        z, cb, rowidx, offsets, o_zq, o_w);
    finalize_kernel<<<NUM_CODES * CODE_DIM / 256, 256, 0, stream>>>(
        emac, emaw, usage, ws_cnt, ws_loss,
        o_cb, o_cnt, o_w, o_use, o_loss);
}

// Round 9
// 961.364 us; speedup vs baseline: 2.4083x; 2.4083x over previous
//
#include <hip/hip_runtime.h>
#include <stdint.h>

#define NUM_CODES 8192
#define CODE_DIM  64
#define BATCH     65536

typedef float    f32x4 __attribute__((ext_vector_type(4)));
typedef _Float16 half8 __attribute__((ext_vector_type(8)));
typedef uint32_t u32;

#define MFMA(a, b, c) __builtin_amdgcn_mfma_f32_16x16x32_f16(a, b, c, 0, 0, 0)

// ---- workspace layout (byte offsets); total = 2,162,692 B (== proven bound)
#define WS_CSQ_OFF   0u           // 8192 f32
#define WS_CNT_OFF   32768u       // 8192 f32 (histogram, zeroed)
#define WS_CBH_OFF   65536u       // 8192*64 f16 hi, chunk-swizzled
#define WS_CBL_OFF   1114112u     // 8192*64 f16 lo*2048
#define WS_LOSS_OFF  2162688u     // 1 f32

#define BUFB 16640               // 8KB hi + 8KB lo + 256B csq per 64-code tile

__device__ __forceinline__ void gload16(const void* g, void* l) {
    __builtin_amdgcn_global_load_lds(
        (const __attribute__((address_space(1))) void*)g,
        (__attribute__((address_space(3))) void*)l,
        16, 0, 0);
}

// ---------------------------------------------------------------------------
// Prep: split codebook into f16 hi + 2048*lo with chunk-XOR swizzle, + csq.
// ---------------------------------------------------------------------------
__global__ void split_cb_kernel(const float* __restrict__ cb,
                                char* __restrict__ cbh, char* __restrict__ cbl,
                                float* __restrict__ csq) {
    int gid  = blockIdx.x * 256 + threadIdx.x;   // 65536 total
    int code = gid >> 3;
    int c    = gid & 7;
    const float* p = cb + (size_t)code * CODE_DIM + c * 8;
    f32x4 u0 = *(const f32x4*)p;
    f32x4 u1 = *(const f32x4*)(p + 4);
    half8 h, lo;
    float ssq = 0.f;
#pragma unroll
    for (int i = 0; i < 4; ++i) {
        float v0 = u0[i], v1 = u1[i];
        ssq = fmaf(v0, v0, ssq); ssq = fmaf(v1, v1, ssq);
        _Float16 h0 = (_Float16)v0, h1 = (_Float16)v1;
        h[i] = h0;     h[i + 4] = h1;
        lo[i]     = (_Float16)((v0 - (float)h0) * 2048.f);
        lo[i + 4] = (_Float16)((v1 - (float)h1) * 2048.f);
    }
    int slot = code * 8 + (c ^ (code & 7));
    ((half8*)cbh)[slot] = h;
    ((half8*)cbl)[slot] = lo;
    ssq += __shfl_xor(ssq, 1, 64);
    ssq += __shfl_xor(ssq, 2, 64);
    ssq += __shfl_xor(ssq, 4, 64);
    if (c == 0) csq[code] = ssq;
}

// ---------------------------------------------------------------------------
// Fused distance + argmin via split-f16 MFMA.
// 256 thr = 4 waves (2 row-halves x 2 code-halves); block = 128 rows.
// Tile = 64 codes; LDS = 2 x 16.6KB -> 4 blocks/CU (16 waves/CU).
// score = csq - 2 z.cb ; dot = ah.bh + (ah.bl + al.bh)/2048 (lolo dropped,
// residual ~5e-7 << the 4e-6 split-rounding noise that already passes).
// Fused: counts histogram + commitment loss sum(zsq + minv).
// ---------------------------------------------------------------------------
__global__ __launch_bounds__(256, 4)
void argmin_mfma_kernel(const float* __restrict__ z, const char* __restrict__ cbh,
                        const char* __restrict__ cbl, const char* __restrict__ csq_b,
                        float* __restrict__ codes_out, float* __restrict__ ws_counts,
                        float* __restrict__ ws_loss) {
    __shared__ __align__(16) char lds[2 * BUFB];   // 33280 B
    const int tid    = threadIdx.x;
    const int lane   = tid & 63;
    const int w      = tid >> 6;          // 0..3
    const int wr     = w >> 1, wc = w & 1;
    const int lane_r = lane & 15, lg = lane >> 4;
    const int brow   = blockIdx.x * 128 + wr * 64;

    // ---- A fragments (-2z split) + per-row zsq ----
    half8 ah[4][2], al[4][2];
    float zsq[4];
#pragma unroll
    for (int m = 0; m < 4; ++m) {
        const float* zp = z + (size_t)(brow + m * 16 + lane_r) * CODE_DIM;
        float ssq = 0.f;
#pragma unroll
        for (int ks = 0; ks < 2; ++ks) {
            f32x4 u0 = *(const f32x4*)(zp + ks * 32 + lg * 8);
            f32x4 u1 = *(const f32x4*)(zp + ks * 32 + lg * 8 + 4);
            half8 h, lo;
#pragma unroll
            for (int i = 0; i < 4; ++i) {
                ssq = fmaf(u0[i], u0[i], ssq); ssq = fmaf(u1[i], u1[i], ssq);
                float a0 = -2.f * u0[i];
                _Float16 h0 = (_Float16)a0;
                h[i] = h0; lo[i] = (_Float16)((a0 - (float)h0) * 2048.f);
                float a1 = -2.f * u1[i];
                _Float16 h1 = (_Float16)a1;
                h[i + 4] = h1; lo[i + 4] = (_Float16)((a1 - (float)h1) * 2048.f);
            }
            ah[m][ks] = h; al[m][ks] = lo;
        }
        ssq += __shfl_xor(ssq, 16, 64);    // reduce across lg (k-chunks)
        ssq += __shfl_xor(ssq, 32, 64);
        zsq[m] = ssq;
    }

    float minv[16]; int mini[16];
#pragma unroll
    for (int i = 0; i < 16; ++i) { minv[i] = 3.4e38f; mini[i] = 0; }

    // ---- prologue: tile 0 into buffer 0 (4 (+1) gload16 per thread) ----
    {
        gload16(cbh + tid * 16,        lds + tid * 16);
        gload16(cbh + 4096 + tid * 16, lds + 4096 + tid * 16);
        gload16(cbl + tid * 16,        lds + 8192 + tid * 16);
        gload16(cbl + 4096 + tid * 16, lds + 12288 + tid * 16);
        if (tid < 16) gload16(csq_b + tid * 16, lds + 16384 + tid * 16);
    }
    __syncthreads();

    int buf = 0;
#pragma unroll 1
    for (int t = 0; t < NUM_CODES / 64; ++t) {
        if (t < NUM_CODES / 64 - 1) {
            char* dst = lds + (buf ^ 1) * BUFB;
            const char* srch = cbh + (size_t)(t + 1) * 8192;
            const char* srcl = cbl + (size_t)(t + 1) * 8192;
            gload16(srch + tid * 16,        dst + tid * 16);
            gload16(srch + 4096 + tid * 16, dst + 4096 + tid * 16);
            gload16(srcl + tid * 16,        dst + 8192 + tid * 16);
            gload16(srcl + 4096 + tid * 16, dst + 12288 + tid * 16);
            if (tid < 16)
                gload16(csq_b + (size_t)(t + 1) * 256 + tid * 16,
                        dst + 16384 + tid * 16);
        }

        const char*  bh_p = lds + buf * BUFB;
        const char*  bl_p = bh_p + 8192;
        const float* cs_p = (const float*)(bh_p + 16384);
        const int cbase = t * 64 + wc * 32;
#pragma unroll
        for (int n = 0; n < 2; ++n) {
            const int rt  = wc * 32 + n * 16 + lane_r;   // code within tile
            const int sw  = rt & 7;
            const int rb  = rt * 128;
            half8 bh0 = *(const half8*)(bh_p + rb + (((0 + lg) ^ sw) << 4));
            half8 bh1 = *(const half8*)(bh_p + rb + (((4 + lg) ^ sw) << 4));
            half8 bl0 = *(const half8*)(bl_p + rb + (((0 + lg) ^ sw) << 4));
            half8 bl1 = *(const half8*)(bl_p + rb + (((4 + lg) ^ sw) << 4));
            float cs  = cs_p[rt];                        // LDS, no vmcnt
            f32x4 cini = {cs, cs, cs, cs};
            f32x4 zero = {0.f, 0.f, 0.f, 0.f};
            int idxv = cbase + n * 16 + lane_r;
#pragma unroll
            for (int m = 0; m < 4; ++m) {
                f32x4 hi = MFMA(ah[m][0], bh0, cini);
                hi = MFMA(ah[m][1], bh1, hi);
                f32x4 mid = MFMA(ah[m][0], bl0, zero);
                mid = MFMA(al[m][0], bh0, mid);
                mid = MFMA(ah[m][1], bl1, mid);
                mid = MFMA(al[m][1], bh1, mid);
#pragma unroll
                for (int j = 0; j < 4; ++j) {
                    float s = fmaf(mid[j], 4.8828125e-4f, hi[j]);  // hi + mid/2048
                    bool lt = s < minv[m * 4 + j];
                    minv[m * 4 + j] = lt ? s : minv[m * 4 + j];
                    mini[m * 4 + j] = lt ? idxv : mini[m * 4 + j];
                }
            }
        }
        __syncthreads();
        buf ^= 1;
    }

    // ---- reduce across the 16 code-lanes ----
#pragma unroll
    for (int s = 1; s < 16; s <<= 1) {
#pragma unroll
        for (int i = 0; i < 16; ++i) {
            float ov = __shfl_xor(minv[i], s, 64);
            int   oi = __shfl_xor(mini[i], s, 64);
            if (ov < minv[i] || (ov == minv[i] && oi < mini[i])) {
                minv[i] = ov; mini[i] = oi;
            }
        }
    }

    // ---- merge wc pair via LDS; write codes/counts; loss partial ----
    float* smv = (float*)lds;              // 128 rows
    int*   smi = (int*)(lds + 512);
    if (wc == 1 && lane_r == 0) {
#pragma unroll
        for (int m = 0; m < 4; ++m)
#pragma unroll
            for (int j = 0; j < 4; ++j) {
                int rl = wr * 64 + m * 16 + lg * 4 + j;
                smv[rl] = minv[m * 4 + j]; smi[rl] = mini[m * 4 + j];
            }
    }
    __syncthreads();
    float lsum = 0.f;
    if (wc == 0) {
        lsum = 0.25f * (zsq[0] + zsq[1] + zsq[2] + zsq[3]);  // lg-replicated x4
        if (lane_r == 0) {
#pragma unroll
            for (int m = 0; m < 4; ++m)
#pragma unroll
                for (int j = 0; j < 4; ++j) {
                    int rl = wr * 64 + m * 16 + lg * 4 + j;
                    float mv = minv[m * 4 + j]; int mi = mini[m * 4 + j];
                    float ov = smv[rl]; int oi = smi[rl];
                    if (ov < mv || (ov == mv && oi < mi)) { mv = ov; mi = oi; }
                    codes_out[blockIdx.x * 128 + rl] = (float)mi;
                    atomicAdd(&ws_counts[mi], 1.0f);
                    lsum += mv;            // ||z-c||^2 = zsq + minv
                }
        }
    }
#pragma unroll
    for (int s = 1; s < 64; s <<= 1) lsum += __shfl_xor(lsum, s, 64);
    if (lane == 0 && wc == 0) atomicAdd(ws_loss, lsum);
}

// ---------------------------------------------------------------------------
// Exclusive scan of counts -> offsets[8193] + cursor. 1 block, 256 thr.
// ---------------------------------------------------------------------------
__global__ void scan_kernel(const float* __restrict__ cnt,
                            u32* __restrict__ offsets, u32* __restrict__ cursor) {
    __shared__ u32 wsum[4];
    int t = threadIdx.x, lane = t & 63, w = t >> 6;
    u32 v[32], s = 0;
#pragma unroll
    for (int i = 0; i < 32; ++i) { v[i] = (u32)cnt[t * 32 + i]; s += v[i]; }
    u32 inc = s;
#pragma unroll
    for (int d = 1; d < 64; d <<= 1) {
        u32 x = __shfl_up(inc, d, 64);
        if (lane >= d) inc += x;
    }
    if (lane == 63) wsum[w] = inc;
    __syncthreads();
    u32 base = 0;
    for (int i = 0; i < w; ++i) base += wsum[i];
    u32 excl = base + inc - s;
#pragma unroll
    for (int i = 0; i < 32; ++i) {
        offsets[t * 32 + i] = excl;
        cursor [t * 32 + i] = excl;
        excl += v[i];
    }
    if (t == 255) offsets[8192] = excl;
}

// ---------------------------------------------------------------------------
// Place rows into code-sorted order: one atomic per row.
// ---------------------------------------------------------------------------
__global__ void place_kernel(const float* __restrict__ codes_f,
                             u32* __restrict__ cursor, u32* __restrict__ rowidx) {
    int row = blockIdx.x * 256 + threadIdx.x;
    int c = (int)codes_f[row];
    u32 pos = atomicAdd(&cursor[c], 1u);
    rowidx[pos] = (u32)row;
}

// ---------------------------------------------------------------------------
// Segmented sum + z_q write: one wave per code, lane = dim. Zero atomics.
// ---------------------------------------------------------------------------
__global__ void segsum_zq_kernel(const float* __restrict__ z,
                                 const float* __restrict__ cb,
                                 const u32* __restrict__ rowidx,
                                 const u32* __restrict__ offsets,
                                 float* __restrict__ zq_out,
                                 float* __restrict__ asum) {
    int gw   = (blockIdx.x * 256 + threadIdx.x) >> 6;   // code id
    int lane = threadIdx.x & 63;
    float cbv = cb[(size_t)gw * CODE_DIM + lane];
    u32 beg = offsets[gw], end = offsets[gw + 1];
    float acc = 0.f;
    for (u32 i = beg; i < end; ++i) {
        u32 r = rowidx[i];
        acc += z[(size_t)r * CODE_DIM + lane];
        zq_out[(size_t)r * CODE_DIM + lane] = cbv;
    }
    asum[(size_t)gw * CODE_DIM + lane] = acc;
}

// ---------------------------------------------------------------------------
// EMA finalize + losses. asum aliases out_weight (read-then-overwrite).
// ---------------------------------------------------------------------------
__global__ void finalize_kernel(const float* __restrict__ ema_count,
                                const float* __restrict__ ema_weight,
                                const float* __restrict__ usage,
                                const float* __restrict__ ws_counts,
                                const float* __restrict__ ws_loss,
                                float* __restrict__ out_codebook, float* __restrict__ out_count,
                                float* __restrict__ out_weight,   float* __restrict__ out_usage,
                                float* __restrict__ out_losses) {
    int gid = blockIdx.x * 256 + threadIdx.x;
    if (gid >= NUM_CODES * CODE_DIM) return;
    int c = gid >> 6;
    float cnt  = ws_counts[c];
    float ncnt = 0.99f * ema_count[c] + 0.01f * cnt;
    float nw   = 0.99f * ema_weight[gid] + 0.01f * out_weight[gid];  // asum alias
    out_weight[gid]   = nw;
    out_codebook[gid] = nw / (ncnt + 1e-5f);
    if ((gid & 63) == 0) {
        out_count[c] = ncnt;
        out_usage[c] = usage[c] + cnt;
    }
    if (gid == 0) {
        float s = ws_loss[0] * (1.0f / ((float)BATCH * (float)CODE_DIM));
        out_losses[0] = s;
        out_losses[1] = s;
        out_losses[2] = fmaf(0.25f, s, s);
    }
}

// ---------------------------------------------------------------------------
extern "C" void kernel_launch(void* const* d_in, const int* in_sizes, int n_in,
                              void* d_out, int out_size, void* d_ws, size_t ws_size,
                              hipStream_t stream) {
    const float* z     = (const float*)d_in[0];
    const float* cb    = (const float*)d_in[1];
    const float* emac  = (const float*)d_in[2];
    const float* emaw  = (const float*)d_in[3];
    const float* usage = (const float*)d_in[4];

    float* out = (float*)d_out;
    float* o_zq    = out;                    // 4194304
    float* o_codes = out + 4194304;          // 65536
    float* o_loss  = out + 4194304 + 65536;  // 3
    float* o_cb    = o_loss + 3;             // 524288 (scratch until finalize)
    float* o_cnt   = o_cb + 524288;          // 8192
    float* o_w     = o_cnt + 8192;           // 524288 (asum, then weight)
    float* o_use   = o_w + 524288;           // 8192

    // sort scratch inside o_cb region (finalize overwrites it last)
    u32* rowidx  = (u32*)o_cb;               // [0, 65536)
    u32* offsets = rowidx + 65536;           // [65536, 73729)
    u32* cursor  = rowidx + 81920;           // [81920, 90112)

    char*  wsb     = (char*)d_ws;
    float* ws_csq  = (float*)(wsb + WS_CSQ_OFF);
    float* ws_cnt  = (float*)(wsb + WS_CNT_OFF);
    char*  ws_cbh  = wsb + WS_CBH_OFF;
    char*  ws_cbl  = wsb + WS_CBL_OFF;
    float* ws_loss = (float*)(wsb + WS_LOSS_OFF);

    hipMemsetAsync(wsb + WS_CNT_OFF, 0, 32768, stream);   // counts histogram
    hipMemsetAsync(wsb + WS_LOSS_OFF, 0, 4, stream);      // loss accumulator

    split_cb_kernel<<<256, 256, 0, stream>>>(cb, ws_cbh, ws_cbl, ws_csq);
    argmin_mfma_kernel<<<BATCH / 128, 256, 0, stream>>>(
        z, ws_cbh, ws_cbl, (const char*)ws_csq, o_codes, ws_cnt, ws_loss);
    scan_kernel<<<1, 256, 0, stream>>>(ws_cnt, offsets, cursor);
    place_kernel<<<BATCH / 256, 256, 0, stream>>>(o_codes, cursor, rowidx);
    segsum_zq_kernel<<<NUM_CODES * 64 / 256, 256, 0, stream>>>(
        z, cb, rowidx, offsets, o_zq, o_w);
    finalize_kernel<<<NUM_CODES * CODE_DIM / 256, 256, 0, stream>>>(
        emac, emaw, usage, ws_cnt, ws_loss,
        o_cb, o_cnt, o_w, o_use, o_loss);
}

// Round 10
// 409.165 us; speedup vs baseline: 5.6585x; 2.3496x over previous
//
#include <hip/hip_runtime.h>
#include <stdint.h>

#define NUM_CODES 8192
#define CODE_DIM  64
#define BATCH     65536

typedef float    f32x4 __attribute__((ext_vector_type(4)));
typedef _Float16 half8 __attribute__((ext_vector_type(8)));
typedef uint32_t u32;

#define MFMA(a, b, c) __builtin_amdgcn_mfma_f32_16x16x32_f16(a, b, c, 0, 0, 0)

// ---- workspace layout (byte offsets); total = 2,162,692 B (== proven bound)
#define WS_CSQ_OFF   0u           // 8192 f32
#define WS_CNT_OFF   32768u       // 8192 f32 (histogram, zeroed)
#define WS_CBH_OFF   65536u       // 8192*64 f16 hi, chunk-swizzled
#define WS_CBL_OFF   1114112u     // 8192*64 f16 lo*2048
#define WS_LOSS_OFF  2162688u     // 1 f32

#define BUFB 16640               // 8KB hi + 8KB lo + 256B csq per 64-code tile

__device__ __forceinline__ void gload16(const void* g, void* l) {
    __builtin_amdgcn_global_load_lds(
        (const __attribute__((address_space(1))) void*)g,
        (__attribute__((address_space(3))) void*)l,
        16, 0, 0);
}

// ---------------------------------------------------------------------------
// Prep: split codebook into f16 hi + 2048*lo with chunk-XOR swizzle, + csq.
// ---------------------------------------------------------------------------
__global__ void split_cb_kernel(const float* __restrict__ cb,
                                char* __restrict__ cbh, char* __restrict__ cbl,
                                float* __restrict__ csq) {
    int gid  = blockIdx.x * 256 + threadIdx.x;   // 65536 total
    int code = gid >> 3;
    int c    = gid & 7;
    const float* p = cb + (size_t)code * CODE_DIM + c * 8;
    f32x4 u0 = *(const f32x4*)p;
    f32x4 u1 = *(const f32x4*)(p + 4);
    half8 h, lo;
    float ssq = 0.f;
#pragma unroll
    for (int i = 0; i < 4; ++i) {
        float v0 = u0[i], v1 = u1[i];
        ssq = fmaf(v0, v0, ssq); ssq = fmaf(v1, v1, ssq);
        _Float16 h0 = (_Float16)v0, h1 = (_Float16)v1;
        h[i] = h0;     h[i + 4] = h1;
        lo[i]     = (_Float16)((v0 - (float)h0) * 2048.f);
        lo[i + 4] = (_Float16)((v1 - (float)h1) * 2048.f);
    }
    int slot = code * 8 + (c ^ (code & 7));
    ((half8*)cbh)[slot] = h;
    ((half8*)cbl)[slot] = lo;
    ssq += __shfl_xor(ssq, 1, 64);
    ssq += __shfl_xor(ssq, 2, 64);
    ssq += __shfl_xor(ssq, 4, 64);
    if (c == 0) csq[code] = ssq;
}

// ---------------------------------------------------------------------------
// Fused distance + argmin via split-f16 MFMA.
// 256 thr = 4 waves (2 row-halves x 2 code-halves); block = 128 rows.
// Tile = 64 codes; LDS = 2 x 16.6KB. __launch_bounds__(256,2): cap 256 regs
// (the r5-proven allocator regime -- (256,4)/(512,4) both spilled: unified
// VGPR/AGPR file splits the 128-reg budget 64+64 and the 64 arch VGPRs
// can't hold the A-fragments).
// score = csq - 2 z.cb ; dot = ah.bh + (ah.bl + al.bh)/2048.
// Fused: counts histogram + commitment loss sum(zsq + minv).
// ---------------------------------------------------------------------------
__global__ __launch_bounds__(256, 2)
void argmin_mfma_kernel(const float* __restrict__ z, const char* __restrict__ cbh,
                        const char* __restrict__ cbl, const char* __restrict__ csq_b,
                        float* __restrict__ codes_out, float* __restrict__ ws_counts,
                        float* __restrict__ ws_loss) {
    __shared__ __align__(16) char lds[2 * BUFB];   // 33280 B
    const int tid    = threadIdx.x;
    const int lane   = tid & 63;
    const int w      = tid >> 6;          // 0..3
    const int wr     = w >> 1, wc = w & 1;
    const int lane_r = lane & 15, lg = lane >> 4;
    const int brow   = blockIdx.x * 128 + wr * 64;

    // ---- A fragments (-2z split) + per-row zsq ----
    half8 ah[4][2], al[4][2];
    float zsq[4];
#pragma unroll
    for (int m = 0; m < 4; ++m) {
        const float* zp = z + (size_t)(brow + m * 16 + lane_r) * CODE_DIM;
        float ssq = 0.f;
#pragma unroll
        for (int ks = 0; ks < 2; ++ks) {
            f32x4 u0 = *(const f32x4*)(zp + ks * 32 + lg * 8);
            f32x4 u1 = *(const f32x4*)(zp + ks * 32 + lg * 8 + 4);
            half8 h, lo;
#pragma unroll
            for (int i = 0; i < 4; ++i) {
                ssq = fmaf(u0[i], u0[i], ssq); ssq = fmaf(u1[i], u1[i], ssq);
                float a0 = -2.f * u0[i];
                _Float16 h0 = (_Float16)a0;
                h[i] = h0; lo[i] = (_Float16)((a0 - (float)h0) * 2048.f);
                float a1 = -2.f * u1[i];
                _Float16 h1 = (_Float16)a1;
                h[i + 4] = h1; lo[i + 4] = (_Float16)((a1 - (float)h1) * 2048.f);
            }
            ah[m][ks] = h; al[m][ks] = lo;
        }
        ssq += __shfl_xor(ssq, 16, 64);    // reduce across lg (k-chunks)
        ssq += __shfl_xor(ssq, 32, 64);
        zsq[m] = ssq;
    }

    float minv[16]; int mini[16];
#pragma unroll
    for (int i = 0; i < 16; ++i) { minv[i] = 3.4e38f; mini[i] = 0; }

    // ---- prologue: tile 0 into buffer 0 (4 (+1) gload16 per thread) ----
    {
        gload16(cbh + tid * 16,        lds + tid * 16);
        gload16(cbh + 4096 + tid * 16, lds + 4096 + tid * 16);
        gload16(cbl + tid * 16,        lds + 8192 + tid * 16);
        gload16(cbl + 4096 + tid * 16, lds + 12288 + tid * 16);
        if (tid < 16) gload16(csq_b + tid * 16, lds + 16384 + tid * 16);
    }
    __syncthreads();

    int buf = 0;
#pragma unroll 1
    for (int t = 0; t < NUM_CODES / 64; ++t) {
        if (t < NUM_CODES / 64 - 1) {
            char* dst = lds + (buf ^ 1) * BUFB;
            const char* srch = cbh + (size_t)(t + 1) * 8192;
            const char* srcl = cbl + (size_t)(t + 1) * 8192;
            gload16(srch + tid * 16,        dst + tid * 16);
            gload16(srch + 4096 + tid * 16, dst + 4096 + tid * 16);
            gload16(srcl + tid * 16,        dst + 8192 + tid * 16);
            gload16(srcl + 4096 + tid * 16, dst + 12288 + tid * 16);
            if (tid < 16)
                gload16(csq_b + (size_t)(t + 1) * 256 + tid * 16,
                        dst + 16384 + tid * 16);
        }

        const char*  bh_p = lds + buf * BUFB;
        const char*  bl_p = bh_p + 8192;
        const float* cs_p = (const float*)(bh_p + 16384);
        const int cbase = t * 64 + wc * 32;
#pragma unroll
        for (int n = 0; n < 2; ++n) {
            const int rt  = wc * 32 + n * 16 + lane_r;   // code within tile
            const int sw  = rt & 7;
            const int rb  = rt * 128;
            half8 bh0 = *(const half8*)(bh_p + rb + (((0 + lg) ^ sw) << 4));
            half8 bh1 = *(const half8*)(bh_p + rb + (((4 + lg) ^ sw) << 4));
            half8 bl0 = *(const half8*)(bl_p + rb + (((0 + lg) ^ sw) << 4));
            half8 bl1 = *(const half8*)(bl_p + rb + (((4 + lg) ^ sw) << 4));
            float cs  = cs_p[rt];                        // LDS, no vmcnt
            f32x4 cini = {cs, cs, cs, cs};
            f32x4 zero = {0.f, 0.f, 0.f, 0.f};
            int idxv = cbase + n * 16 + lane_r;
#pragma unroll
            for (int m = 0; m < 4; ++m) {
                f32x4 hi = MFMA(ah[m][0], bh0, cini);
                hi = MFMA(ah[m][1], bh1, hi);
                f32x4 mid = MFMA(ah[m][0], bl0, zero);
                mid = MFMA(al[m][0], bh0, mid);
                mid = MFMA(ah[m][1], bl1, mid);
                mid = MFMA(al[m][1], bh1, mid);
#pragma unroll
                for (int j = 0; j < 4; ++j) {
                    float s = fmaf(mid[j], 4.8828125e-4f, hi[j]);  // hi + mid/2048
                    bool lt = s < minv[m * 4 + j];
                    minv[m * 4 + j] = lt ? s : minv[m * 4 + j];
                    mini[m * 4 + j] = lt ? idxv : mini[m * 4 + j];
                }
            }
        }
        __syncthreads();
        buf ^= 1;
    }

    // ---- reduce across the 16 code-lanes ----
#pragma unroll
    for (int s = 1; s < 16; s <<= 1) {
#pragma unroll
        for (int i = 0; i < 16; ++i) {
            float ov = __shfl_xor(minv[i], s, 64);
            int   oi = __shfl_xor(mini[i], s, 64);
            if (ov < minv[i] || (ov == minv[i] && oi < mini[i])) {
                minv[i] = ov; mini[i] = oi;
            }
        }
    }

    // ---- merge wc pair via LDS; write codes/counts; loss partial ----
    float* smv = (float*)lds;              // 128 rows
    int*   smi = (int*)(lds + 512);
    if (wc == 1 && lane_r == 0) {
#pragma unroll
        for (int m = 0; m < 4; ++m)
#pragma unroll
            for (int j = 0; j < 4; ++j) {
                int rl = wr * 64 + m * 16 + lg * 4 + j;
                smv[rl] = minv[m * 4 + j]; smi[rl] = mini[m * 4 + j];
            }
    }
    __syncthreads();
    float lsum = 0.f;
    if (wc == 0) {
        lsum = 0.25f * (zsq[0] + zsq[1] + zsq[2] + zsq[3]);  // lg-replicated x4
        if (lane_r == 0) {
#pragma unroll
            for (int m = 0; m < 4; ++m)
#pragma unroll
                for (int j = 0; j < 4; ++j) {
                    int rl = wr * 64 + m * 16 + lg * 4 + j;
                    float mv = minv[m * 4 + j]; int mi = mini[m * 4 + j];
                    float ov = smv[rl]; int oi = smi[rl];
                    if (ov < mv || (ov == mv && oi < mi)) { mv = ov; mi = oi; }
                    codes_out[blockIdx.x * 128 + rl] = (float)mi;
                    atomicAdd(&ws_counts[mi], 1.0f);
                    lsum += mv;            // ||z-c||^2 = zsq + minv
                }
        }
    }
#pragma unroll
    for (int s = 1; s < 64; s <<= 1) lsum += __shfl_xor(lsum, s, 64);
    if (lane == 0 && wc == 0) atomicAdd(ws_loss, lsum);
}

// ---------------------------------------------------------------------------
// Exclusive scan of counts -> offsets[8193] + cursor. 1 block, 256 thr.
// ---------------------------------------------------------------------------
__global__ void scan_kernel(const float* __restrict__ cnt,
                            u32* __restrict__ offsets, u32* __restrict__ cursor) {
    __shared__ u32 wsum[4];
    int t = threadIdx.x, lane = t & 63, w = t >> 6;
    u32 v[32], s = 0;
#pragma unroll
    for (int i = 0; i < 32; ++i) { v[i] = (u32)cnt[t * 32 + i]; s += v[i]; }
    u32 inc = s;
#pragma unroll
    for (int d = 1; d < 64; d <<= 1) {
        u32 x = __shfl_up(inc, d, 64);
        if (lane >= d) inc += x;
    }
    if (lane == 63) wsum[w] = inc;
    __syncthreads();
    u32 base = 0;
    for (int i = 0; i < w; ++i) base += wsum[i];
    u32 excl = base + inc - s;
#pragma unroll
    for (int i = 0; i < 32; ++i) {
        offsets[t * 32 + i] = excl;
        cursor [t * 32 + i] = excl;
        excl += v[i];
    }
    if (t == 255) offsets[8192] = excl;
}

// ---------------------------------------------------------------------------
// Place rows into code-sorted order: one atomic per row.
// ---------------------------------------------------------------------------
__global__ void place_kernel(const float* __restrict__ codes_f,
                             u32* __restrict__ cursor, u32* __restrict__ rowidx) {
    int row = blockIdx.x * 256 + threadIdx.x;
    int c = (int)codes_f[row];
    u32 pos = atomicAdd(&cursor[c], 1u);
    rowidx[pos] = (u32)row;
}

// ---------------------------------------------------------------------------
// Segmented sum + z_q write: one wave per code, lane = dim. Zero atomics.
// ---------------------------------------------------------------------------
__global__ void segsum_zq_kernel(const float* __restrict__ z,
                                 const float* __restrict__ cb,
                                 const u32* __restrict__ rowidx,
                                 const u32* __restrict__ offsets,
                                 float* __restrict__ zq_out,
                                 float* __restrict__ asum) {
    int gw   = (blockIdx.x * 256 + threadIdx.x) >> 6;   // code id
    int lane = threadIdx.x & 63;
    float cbv = cb[(size_t)gw * CODE_DIM + lane];
    u32 beg = offsets[gw], end = offsets[gw + 1];
    float acc = 0.f;
    for (u32 i = beg; i < end; ++i) {
        u32 r = rowidx[i];
        acc += z[(size_t)r * CODE_DIM + lane];
        zq_out[(size_t)r * CODE_DIM + lane] = cbv;
    }
    asum[(size_t)gw * CODE_DIM + lane] = acc;
}

// ---------------------------------------------------------------------------
// EMA finalize + losses. asum aliases out_weight (read-then-overwrite).
// ---------------------------------------------------------------------------
__global__ void finalize_kernel(const float* __restrict__ ema_count,
                                const float* __restrict__ ema_weight,
                                const float* __restrict__ usage,
                                const float* __restrict__ ws_counts,
                                const float* __restrict__ ws_loss,
                                float* __restrict__ out_codebook, float* __restrict__ out_count,
                                float* __restrict__ out_weight,   float* __restrict__ out_usage,
                                float* __restrict__ out_losses) {
    int gid = blockIdx.x * 256 + threadIdx.x;
    if (gid >= NUM_CODES * CODE_DIM) return;
    int c = gid >> 6;
    float cnt  = ws_counts[c];
    float ncnt = 0.99f * ema_count[c] + 0.01f * cnt;
    float nw   = 0.99f * ema_weight[gid] + 0.01f * out_weight[gid];  // asum alias
    out_weight[gid]   = nw;
    out_codebook[gid] = nw / (ncnt + 1e-5f);
    if ((gid & 63) == 0) {
        out_count[c] = ncnt;
        out_usage[c] = usage[c] + cnt;
    }
    if (gid == 0) {
        float s = ws_loss[0] * (1.0f / ((float)BATCH * (float)CODE_DIM));
        out_losses[0] = s;
        out_losses[1] = s;
        out_losses[2] = fmaf(0.25f, s, s);
    }
}

// ---------------------------------------------------------------------------
extern "C" void kernel_launch(void* const* d_in, const int* in_sizes, int n_in,
                              void* d_out, int out_size, void* d_ws, size_t ws_size,
                              hipStream_t stream) {
    const float* z     = (const float*)d_in[0];
    const float* cb    = (const float*)d_in[1];
    const float* emac  = (const float*)d_in[2];
    const float* emaw  = (const float*)d_in[3];
    const float* usage = (const float*)d_in[4];

    float* out = (float*)d_out;
    float* o_zq    = out;                    // 4194304
    float* o_codes = out + 4194304;          // 65536
    float* o_loss  = out + 4194304 + 65536;  // 3
    float* o_cb    = o_loss + 3;             // 524288 (scratch until finalize)
    float* o_cnt   = o_cb + 524288;          // 8192
    float* o_w     = o_cnt + 8192;           // 524288 (asum, then weight)
    float* o_use   = o_w + 524288;           // 8192

    // sort scratch inside o_cb region (finalize overwrites it last)
    u32* rowidx  = (u32*)o_cb;               // [0, 65536)
    u32* offsets = rowidx + 65536;           // [65536, 73729)
    u32* cursor  = rowidx + 81920;           // [81920, 90112)

    char*  wsb     = (char*)d_ws;
    float* ws_csq  = (float*)(wsb + WS_CSQ_OFF);
    float* ws_cnt  = (float*)(wsb + WS_CNT_OFF);
    char*  ws_cbh  = wsb + WS_CBH_OFF;
    char*  ws_cbl  = wsb + WS_CBL_OFF;
    float* ws_loss = (float*)(wsb + WS_LOSS_OFF);

    hipMemsetAsync(wsb + WS_CNT_OFF, 0, 32768, stream);   // counts histogram
    hipMemsetAsync(wsb + WS_LOSS_OFF, 0, 4, stream);      // loss accumulator

    split_cb_kernel<<<256, 256, 0, stream>>>(cb, ws_cbh, ws_cbl, ws_csq);
    argmin_mfma_kernel<<<BATCH / 128, 256, 0, stream>>>(
        z, ws_cbh, ws_cbl, (const char*)ws_csq, o_codes, ws_cnt, ws_loss);
    scan_kernel<<<1, 256, 0, stream>>>(ws_cnt, offsets, cursor);
    place_kernel<<<BATCH / 256, 256, 0, stream>>>(o_codes, cursor, rowidx);
    segsum_zq_kernel<<<NUM_CODES * 64 / 256, 256, 0, stream>>>(
        z, cb, rowidx, offsets, o_zq, o_w);
    finalize_kernel<<<NUM_CODES * CODE_DIM / 256, 256, 0, stream>>>(
        emac, emaw, usage, ws_cnt, ws_loss,
        o_cb, o_cnt, o_w, o_use, o_loss);
}